// Round 9
// baseline (118.922 us; speedup 1.0000x reference)
//
#include <hip/hip_runtime.h>
#include <hip/hip_bf16.h>

// NT-Xent with more negatives: N=2048, D=128, k=4 augs.
// sim = norm(z[4096,128]) @ norm(z_all[8192,128])^T * 2   (T=0.5)
// loss = mean_rows( logsumexp(masked sim) - pos )
// R9 = MEASUREMENT ROUND: R7 kernel verbatim, but kgemm is launched TWICE
// (idempotent: pS is pure stores). Total - 105.6 gives kgemm's true duration,
// which has been invisible under the harness's 42us fill dispatches since R5.
// If kgemm >= ~41us both copies appear in rocprof top-5 -> direct reading +
// first-vs-second = DVFS/cache-warmup signature.

#define NN      2048
#define DD      128
#define TWO_N   4096
#define FOUR_N  8192
#define BM      128
#define BN      128
#define GT      8      // B-tiles streamed per block
#define CTG     8      // col groups (8192 / (BN*GT))

using frag_ab = __attribute__((ext_vector_type(8))) short;  // 8 bf16 = 16 B
using f32x4   = __attribute__((ext_vector_type(4))) float;

__device__ inline void gl_lds16(const short* g, short* l) {
  __builtin_amdgcn_global_load_lds(
      (const __attribute__((address_space(1))) void*)g,
      (__attribute__((address_space(3))) void*)l, 16, 0, 0);
}

// XOR swizzle: LDS chunk (row,pos) holds global chunk (row, pos^(row&15)).
// Kills the 16-way ds_read_b128 bank conflict (verified R3: 7.34M -> 0).
__device__ inline int swz(int chunk) {
  return (chunk & ~15) | ((chunk & 15) ^ ((chunk >> 4) & 15));
}

// ---------------- Kernel 1: L2-normalize rows -> bf16; zero out ----------
__global__ __launch_bounds__(256) void knorm(const float* __restrict__ p0,
                                             const float* __restrict__ p1,
                                             const float* __restrict__ p2,
                                             const float* __restrict__ p3,
                                             short* __restrict__ Bn,
                                             float* __restrict__ out) {
  if (blockIdx.x == 0 && threadIdx.x == 0) out[0] = 0.0f;
  int wave = threadIdx.x >> 6, lane = threadIdx.x & 63;
  int row = blockIdx.x * 4 + wave;                 // 0..8191
  int q = row >> 11, idx = row & (NN - 1);
  const float* src = (q == 0) ? p0 : (q == 1) ? p1 : (q == 2) ? p2 : p3;
  const float2* s2 = (const float2*)(src + (size_t)idx * DD);
  float2 v = s2[lane];
  float ss = v.x * v.x + v.y * v.y;
  #pragma unroll
  for (int sh = 1; sh < 64; sh <<= 1) ss += __shfl_xor(ss, sh, 64);
  float inv = 1.0f / fmaxf(sqrtf(ss), 1e-8f);
  __hip_bfloat162 o;
  o.x = __float2bfloat16(v.x * inv);
  o.y = __float2bfloat16(v.y * inv);
  ((__hip_bfloat162*)(Bn + (size_t)row * DD))[lane] = o;
}

// ---------------- Kernel 2: persistent-tile GEMM + partial sumexp ----------
// Grid (32, 8) = 256 blocks = 1/CU. 512 threads = 8 waves = 2/SIMD.
// Block: 128 A-rows x 1024 B-cols (8 streamed 128-col tiles, double-buffered
// global_load_lds prefetch). Wave w: rows (w>>2)*64..+64, cols (w&3)*32..+32.
// pS[row][group] = sum_{cols in group} exp(2*sim - 2).
__global__ __launch_bounds__(512, 1) void kgemm(const short* __restrict__ Bn,
                                                float* __restrict__ pS) {
  __shared__ short sA[BM * DD];        // 32 KB (swizzled)
  __shared__ short sB[2][BN * DD];     // 64 KB (swizzled, double-buffered)
  __shared__ float sS[BM][4];

  int t = threadIdx.x, wave = t >> 6, lane = t & 63;
  int quad = lane >> 4, l16 = lane & 15;
  int rowHalf = wave >> 2, colQ = wave & 3;

  const short* gA = Bn + (size_t)blockIdx.x * BM * DD;
  const short* gB0 = Bn + (size_t)blockIdx.y * (GT * BN) * DD;

  // Stage A + B-tile 0.  2048 chunks per 32 KB tile / 512 threads = 4 each.
  #pragma unroll
  for (int i = 0; i < 4; ++i) {
    int c0 = i * 512 + wave * 64;                  // lane-0 LDS chunk index
    gl_lds16(gA + (size_t)swz(c0 + lane) * 8, sA + (size_t)c0 * 8);
    gl_lds16(gB0 + (size_t)swz(c0 + lane) * 8, sB[0] + (size_t)c0 * 8);
  }
  __syncthreads();

  // Hoist all A fragments (fixed across the 8 B-tiles): a[k][rf].
  frag_ab a[4][4];
  #pragma unroll
  for (int k = 0; k < 4; ++k)
    #pragma unroll
    for (int rf = 0; rf < 4; ++rf) {
      int r_ = rowHalf * 64 + rf * 16 + l16;       // r_ & 15 == l16
      a[k][rf] = *(const frag_ab*)&sA[(size_t)((r_ << 4) | ((k * 4 + quad) ^ l16)) * 8];
    }

  float sAcc[4][4];
  #pragma unroll
  for (int rf = 0; rf < 4; ++rf)
    #pragma unroll
    for (int r = 0; r < 4; ++r) sAcc[rf][r] = 0.f;

  #pragma unroll 1
  for (int g = 0; g < GT; ++g) {
    // Prefetch next B-tile into the other buffer; in flight during compute,
    // so the end-of-iteration barrier's vmcnt(0) drain is nearly free.
    if (g < GT - 1) {
      const short* gBn = gB0 + (size_t)(g + 1) * BN * DD;
      short* dst = sB[(g + 1) & 1];
      #pragma unroll
      for (int i = 0; i < 4; ++i) {
        int c0 = i * 512 + wave * 64;
        gl_lds16(gBn + (size_t)swz(c0 + lane) * 8, dst + (size_t)c0 * 8);
      }
    }
    const short* sBg = sB[g & 1];

    f32x4 acc[4][2];
    #pragma unroll
    for (int rf = 0; rf < 4; ++rf)
      #pragma unroll
      for (int cf = 0; cf < 2; ++cf) acc[rf][cf] = (f32x4){0.f, 0.f, 0.f, 0.f};

    #pragma unroll
    for (int k = 0; k < 4; ++k) {
      frag_ab b[2];
      #pragma unroll
      for (int cf = 0; cf < 2; ++cf) {
        int r_ = colQ * 32 + cf * 16 + l16;
        b[cf] = *(const frag_ab*)&sBg[(size_t)((r_ << 4) | ((k * 4 + quad) ^ l16)) * 8];
      }
      #pragma unroll
      for (int rf = 0; rf < 4; ++rf)
        #pragma unroll
        for (int cf = 0; cf < 2; ++cf)
          acc[rf][cf] = __builtin_amdgcn_mfma_f32_16x16x32_bf16(a[k][rf], b[cf], acc[rf][cf], 0, 0, 0);
    }

    // Register-resident epilogue: accumulate exp(2*sim-2), no shuffles here.
    #pragma unroll
    for (int rf = 0; rf < 4; ++rf)
      #pragma unroll
      for (int r = 0; r < 4; ++r) {
        #pragma unroll
        for (int cf = 0; cf < 2; ++cf)
          sAcc[rf][r] += __expf(fmaf(acc[rf][cf][r], 2.0f, -2.0f));
      }
    __syncthreads();   // publishes the prefetched buffer for iteration g+1
  }

  // One shuffle-reduce per block: fold 16 lanes -> per-row partials per colQ.
  #pragma unroll
  for (int rf = 0; rf < 4; ++rf)
    #pragma unroll
    for (int r = 0; r < 4; ++r) {
      float s = sAcc[rf][r];
      #pragma unroll
      for (int sh = 1; sh < 16; sh <<= 1) s += __shfl_xor(s, sh, 64);
      if (l16 == 0) sS[rowHalf * 64 + rf * 16 + quad * 4 + r][colQ] = s;
    }
  __syncthreads();
  if (t < BM)
    pS[(size_t)(blockIdx.x * BM + t) * CTG + blockIdx.y] =
        (sS[t][0] + sS[t][1]) + (sS[t][2] + sS[t][3]);
}

// ---------------- Kernel 3: finisher (32 blocks x 256 thr) ----------------
// Block b handles rows [b*128, b*128+128): merge 8 group-partials, subtract
// the 3 masked diagonal exps (self, aug3-diag, aug4-diag), add pos term,
// block-reduce, one atomicAdd into out.
__global__ __launch_bounds__(256) void kfin(const short* __restrict__ Bn,
                                            const float* __restrict__ pS,
                                            float* __restrict__ out) {
  int t = threadIdx.x, wave = t >> 6, lane = t & 63;
  int grBase = blockIdx.x * BM;
  __shared__ float sRed[4];

  float wloss = 0.f;                                // valid on lane 0
  for (int rr = wave; rr < BM; rr += 4) {           // 32 rows per wave
    int gr = grBase + rr;
    int idx = gr & (NN - 1), half = gr >> 11;
    float S = (lane < CTG) ? pS[(size_t)gr * CTG + lane] : 0.f;
    #pragma unroll
    for (int sh = 1; sh < 8; sh <<= 1) S += __shfl_xor(S, sh, 64);
    // dots vs: self (gr), pos ((1-half)*NN+idx), aug3 (4096+idx), aug4 (6144+idx)
    unsigned int ua = ((const unsigned int*)(Bn + (size_t)gr * DD))[lane];
    unsigned int ub = ((const unsigned int*)(Bn + (size_t)((1 - half) * NN + idx) * DD))[lane];
    unsigned int uc = ((const unsigned int*)(Bn + (size_t)(2 * NN + idx) * DD))[lane];
    unsigned int ud = ((const unsigned int*)(Bn + (size_t)(3 * NN + idx) * DD))[lane];
    float a0 = __uint_as_float((ua & 0xffffu) << 16), a1 = __uint_as_float(ua & 0xffff0000u);
    float b0 = __uint_as_float((ub & 0xffffu) << 16), b1 = __uint_as_float(ub & 0xffff0000u);
    float c0 = __uint_as_float((uc & 0xffffu) << 16), c1 = __uint_as_float(uc & 0xffff0000u);
    float d0 = __uint_as_float((ud & 0xffffu) << 16), d1 = __uint_as_float(ud & 0xffff0000u);
    float daa = a0 * a0 + a1 * a1;
    float dab = a0 * b0 + a1 * b1;
    float dac = a0 * c0 + a1 * c1;
    float dad = a0 * d0 + a1 * d1;
    #pragma unroll
    for (int sh = 1; sh < 64; sh <<= 1) {
      daa += __shfl_xor(daa, sh, 64);
      dab += __shfl_xor(dab, sh, 64);
      dac += __shfl_xor(dac, sh, 64);
      dad += __shfl_xor(dad, sh, 64);
    }
    // subtract masked diagonals: self + aug3 + aug4 (pos block stays)
    float Sc = S - __expf(fmaf(daa, 2.0f, -2.0f))
                 - __expf(fmaf(dac, 2.0f, -2.0f))
                 - __expf(fmaf(dad, 2.0f, -2.0f));
    float loss = (2.0f + __logf(Sc)) - 2.0f * dab;
    if (lane == 0) wloss += loss;
  }
  if (lane == 0) sRed[wave] = wloss;
  __syncthreads();
  if (t == 0)
    atomicAdd(out, (sRed[0] + sRed[1] + sRed[2] + sRed[3]) * (1.0f / (float)TWO_N));
}

extern "C" void kernel_launch(void* const* d_in, const int* in_sizes, int n_in,
                              void* d_out, int out_size, void* d_ws, size_t ws_size,
                              hipStream_t stream) {
  (void)in_sizes; (void)n_in; (void)out_size; (void)ws_size;
  const float* p0 = (const float*)d_in[0];
  const float* p1 = (const float*)d_in[1];
  const float* p2 = (const float*)d_in[2];
  const float* p3 = (const float*)d_in[3];

  // ws layout: Bn bf16 [8192][128] (2 MB) | pS f32 [4096][8] (128 KB)
  short* Bn = (short*)d_ws;
  float* pS = (float*)((char*)d_ws + (size_t)FOUR_N * DD * sizeof(short));
  float* out = (float*)d_out;

  knorm<<<FOUR_N / 4, 256, 0, stream>>>(p0, p1, p2, p3, Bn, out);
  // PROBE: kgemm launched twice (idempotent — pS is pure stores).
  // Total vs R7 baseline isolates kgemm's true duration.
  kgemm<<<dim3(TWO_N / BM, CTG), 512, 0, stream>>>(Bn, pS);
  kgemm<<<dim3(TWO_N / BM, CTG), 512, 0, stream>>>(Bn, pS);
  kfin<<<TWO_N / BM, 256, 0, stream>>>(Bn, pS, out);
}

// Round 10
// 102.768 us; speedup vs baseline: 1.1572x; 1.1572x over previous
//
#include <hip/hip_runtime.h>
#include <hip/hip_bf16.h>

// NT-Xent with more negatives: N=2048, D=128, k=4 augs.
// sim = norm(z[4096,128]) @ norm(z_all[8192,128])^T * 2   (T=0.5)
// loss = mean_rows( logsumexp(masked sim) - pos )
// Strategy: bf16 MFMA GEMM with fixed softmax max M=2 (cos*2 <= 2), unmasked
// sum of exp(2*sim-2); masked diagonals subtracted analytically in kfin.
// R9 findings: steady-state kgemm = 13.3us, but the first post-fill execution
// runs ~40us — DVFS ramp after the harness's 42us memory-bound 256MB fill
// (all seven prior variants ~32-37K cycles; wall = cycles x ramped clock).
// R10: cut CYCLES via in-block occupancy — 1024 threads = 16 waves = 4
// waves/SIMD (was 2), each wave a 32x32 strip. Same tiles, LDS, staging.

#define NN      2048
#define DD      128
#define TWO_N   4096
#define FOUR_N  8192
#define BM      128
#define BN      128
#define GT      8      // B-tiles streamed per block
#define CTG     8      // col groups (8192 / (BN*GT))

using frag_ab = __attribute__((ext_vector_type(8))) short;  // 8 bf16 = 16 B
using f32x4   = __attribute__((ext_vector_type(4))) float;

__device__ inline void gl_lds16(const short* g, short* l) {
  __builtin_amdgcn_global_load_lds(
      (const __attribute__((address_space(1))) void*)g,
      (__attribute__((address_space(3))) void*)l, 16, 0, 0);
}

// XOR swizzle: LDS chunk (row,pos) holds global chunk (row, pos^(row&15)).
// Kills the 16-way ds_read_b128 bank conflict (verified R3: 7.34M -> 0).
__device__ inline int swz(int chunk) {
  return (chunk & ~15) | ((chunk & 15) ^ ((chunk >> 4) & 15));
}

// ---------------- Kernel 1: L2-normalize rows -> bf16; zero out ----------
__global__ __launch_bounds__(256) void knorm(const float* __restrict__ p0,
                                             const float* __restrict__ p1,
                                             const float* __restrict__ p2,
                                             const float* __restrict__ p3,
                                             short* __restrict__ Bn,
                                             float* __restrict__ out) {
  if (blockIdx.x == 0 && threadIdx.x == 0) out[0] = 0.0f;
  int wave = threadIdx.x >> 6, lane = threadIdx.x & 63;
  int row = blockIdx.x * 4 + wave;                 // 0..8191
  int q = row >> 11, idx = row & (NN - 1);
  const float* src = (q == 0) ? p0 : (q == 1) ? p1 : (q == 2) ? p2 : p3;
  const float2* s2 = (const float2*)(src + (size_t)idx * DD);
  float2 v = s2[lane];
  float ss = v.x * v.x + v.y * v.y;
  #pragma unroll
  for (int sh = 1; sh < 64; sh <<= 1) ss += __shfl_xor(ss, sh, 64);
  float inv = 1.0f / fmaxf(sqrtf(ss), 1e-8f);
  __hip_bfloat162 o;
  o.x = __float2bfloat16(v.x * inv);
  o.y = __float2bfloat16(v.y * inv);
  ((__hip_bfloat162*)(Bn + (size_t)row * DD))[lane] = o;
}

// ---------------- Kernel 2: persistent-tile GEMM + partial sumexp ----------
// Grid (32, 8) = 256 blocks = 1/CU. 1024 threads = 16 waves = 4/SIMD.
// Block: 128 A-rows x 1024 B-cols (8 streamed 128-col tiles, double-buffered
// global_load_lds prefetch). Wave w: rows (w>>2)*32..+32, cols (w&3)*32..+32.
// pS[row][group] = sum_{cols in group} exp(2*sim - 2).
__global__ __launch_bounds__(1024, 4) void kgemm(const short* __restrict__ Bn,
                                                 float* __restrict__ pS) {
  __shared__ short sA[BM * DD];        // 32 KB (swizzled)
  __shared__ short sB[2][BN * DD];     // 64 KB (swizzled, double-buffered)
  __shared__ float sS[BM][4];

  int t = threadIdx.x, wave = t >> 6, lane = t & 63;
  int quad = lane >> 4, l16 = lane & 15;
  int rowQ = wave >> 2, colQ = wave & 3;

  const short* gA = Bn + (size_t)blockIdx.x * BM * DD;
  const short* gB0 = Bn + (size_t)blockIdx.y * (GT * BN) * DD;

  // Stage A + B-tile 0.  2048 chunks per 32 KB tile / 1024 threads = 2 each.
  #pragma unroll
  for (int i = 0; i < 2; ++i) {
    int c0 = i * 1024 + wave * 64;                 // lane-0 LDS chunk index
    gl_lds16(gA + (size_t)swz(c0 + lane) * 8, sA + (size_t)c0 * 8);
    gl_lds16(gB0 + (size_t)swz(c0 + lane) * 8, sB[0] + (size_t)c0 * 8);
  }
  __syncthreads();

  // Hoist A fragments (fixed across the 8 B-tiles): a[k][rf], 32 VGPRs.
  frag_ab a[4][2];
  #pragma unroll
  for (int k = 0; k < 4; ++k)
    #pragma unroll
    for (int rf = 0; rf < 2; ++rf) {
      int r_ = rowQ * 32 + rf * 16 + l16;          // r_ & 15 == l16
      a[k][rf] = *(const frag_ab*)&sA[(size_t)((r_ << 4) | ((k * 4 + quad) ^ l16)) * 8];
    }

  float sAcc[2][4];
  #pragma unroll
  for (int rf = 0; rf < 2; ++rf)
    #pragma unroll
    for (int r = 0; r < 4; ++r) sAcc[rf][r] = 0.f;

  #pragma unroll 1
  for (int g = 0; g < GT; ++g) {
    // Prefetch next B-tile into the other buffer; in flight during compute.
    if (g < GT - 1) {
      const short* gBn = gB0 + (size_t)(g + 1) * BN * DD;
      short* dst = sB[(g + 1) & 1];
      #pragma unroll
      for (int i = 0; i < 2; ++i) {
        int c0 = i * 1024 + wave * 64;
        gl_lds16(gBn + (size_t)swz(c0 + lane) * 8, dst + (size_t)c0 * 8);
      }
    }
    const short* sBg = sB[g & 1];

    f32x4 acc[2][2];
    #pragma unroll
    for (int rf = 0; rf < 2; ++rf)
      #pragma unroll
      for (int cf = 0; cf < 2; ++cf) acc[rf][cf] = (f32x4){0.f, 0.f, 0.f, 0.f};

    #pragma unroll
    for (int k = 0; k < 4; ++k) {
      frag_ab b[2];
      #pragma unroll
      for (int cf = 0; cf < 2; ++cf) {
        int r_ = colQ * 32 + cf * 16 + l16;
        b[cf] = *(const frag_ab*)&sBg[(size_t)((r_ << 4) | ((k * 4 + quad) ^ l16)) * 8];
      }
      #pragma unroll
      for (int rf = 0; rf < 2; ++rf)
        #pragma unroll
        for (int cf = 0; cf < 2; ++cf)
          acc[rf][cf] = __builtin_amdgcn_mfma_f32_16x16x32_bf16(a[k][rf], b[cf], acc[rf][cf], 0, 0, 0);
    }

    // Register-resident epilogue: accumulate exp(2*sim-2).
    #pragma unroll
    for (int rf = 0; rf < 2; ++rf)
      #pragma unroll
      for (int r = 0; r < 4; ++r) {
        #pragma unroll
        for (int cf = 0; cf < 2; ++cf)
          sAcc[rf][r] += __expf(fmaf(acc[rf][cf][r], 2.0f, -2.0f));
      }
    __syncthreads();   // publishes the prefetched buffer for iteration g+1
  }

  // One shuffle-reduce per block: fold 16 lanes -> per-row partials per colQ.
  #pragma unroll
  for (int rf = 0; rf < 2; ++rf)
    #pragma unroll
    for (int r = 0; r < 4; ++r) {
      float s = sAcc[rf][r];
      #pragma unroll
      for (int sh = 1; sh < 16; sh <<= 1) s += __shfl_xor(s, sh, 64);
      if (l16 == 0) sS[rowQ * 32 + rf * 16 + quad * 4 + r][colQ] = s;
    }
  __syncthreads();
  if (t < BM)
    pS[(size_t)(blockIdx.x * BM + t) * CTG + blockIdx.y] =
        (sS[t][0] + sS[t][1]) + (sS[t][2] + sS[t][3]);
}

// ---------------- Kernel 3: finisher (32 blocks x 256 thr) ----------------
// Block b handles rows [b*128, b*128+128): merge 8 group-partials, subtract
// the 3 masked diagonal exps (self, aug3-diag, aug4-diag), add pos term,
// block-reduce, one atomicAdd into out.
__global__ __launch_bounds__(256) void kfin(const short* __restrict__ Bn,
                                            const float* __restrict__ pS,
                                            float* __restrict__ out) {
  int t = threadIdx.x, wave = t >> 6, lane = t & 63;
  int grBase = blockIdx.x * BM;
  __shared__ float sRed[4];

  float wloss = 0.f;                                // valid on lane 0
  for (int rr = wave; rr < BM; rr += 4) {           // 32 rows per wave
    int gr = grBase + rr;
    int idx = gr & (NN - 1), half = gr >> 11;
    float S = (lane < CTG) ? pS[(size_t)gr * CTG + lane] : 0.f;
    #pragma unroll
    for (int sh = 1; sh < 8; sh <<= 1) S += __shfl_xor(S, sh, 64);
    // dots vs: self (gr), pos ((1-half)*NN+idx), aug3 (4096+idx), aug4 (6144+idx)
    unsigned int ua = ((const unsigned int*)(Bn + (size_t)gr * DD))[lane];
    unsigned int ub = ((const unsigned int*)(Bn + (size_t)((1 - half) * NN + idx) * DD))[lane];
    unsigned int uc = ((const unsigned int*)(Bn + (size_t)(2 * NN + idx) * DD))[lane];
    unsigned int ud = ((const unsigned int*)(Bn + (size_t)(3 * NN + idx) * DD))[lane];
    float a0 = __uint_as_float((ua & 0xffffu) << 16), a1 = __uint_as_float(ua & 0xffff0000u);
    float b0 = __uint_as_float((ub & 0xffffu) << 16), b1 = __uint_as_float(ub & 0xffff0000u);
    float c0 = __uint_as_float((uc & 0xffffu) << 16), c1 = __uint_as_float(uc & 0xffff0000u);
    float d0 = __uint_as_float((ud & 0xffffu) << 16), d1 = __uint_as_float(ud & 0xffff0000u);
    float daa = a0 * a0 + a1 * a1;
    float dab = a0 * b0 + a1 * b1;
    float dac = a0 * c0 + a1 * c1;
    float dad = a0 * d0 + a1 * d1;
    #pragma unroll
    for (int sh = 1; sh < 64; sh <<= 1) {
      daa += __shfl_xor(daa, sh, 64);
      dab += __shfl_xor(dab, sh, 64);
      dac += __shfl_xor(dac, sh, 64);
      dad += __shfl_xor(dad, sh, 64);
    }
    // subtract masked diagonals: self + aug3 + aug4 (pos block stays)
    float Sc = S - __expf(fmaf(daa, 2.0f, -2.0f))
                 - __expf(fmaf(dac, 2.0f, -2.0f))
                 - __expf(fmaf(dad, 2.0f, -2.0f));
    float loss = (2.0f + __logf(Sc)) - 2.0f * dab;
    if (lane == 0) wloss += loss;
  }
  if (lane == 0) sRed[wave] = wloss;
  __syncthreads();
  if (t == 0)
    atomicAdd(out, (sRed[0] + sRed[1] + sRed[2] + sRed[3]) * (1.0f / (float)TWO_N));
}

extern "C" void kernel_launch(void* const* d_in, const int* in_sizes, int n_in,
                              void* d_out, int out_size, void* d_ws, size_t ws_size,
                              hipStream_t stream) {
  (void)in_sizes; (void)n_in; (void)out_size; (void)ws_size;
  const float* p0 = (const float*)d_in[0];
  const float* p1 = (const float*)d_in[1];
  const float* p2 = (const float*)d_in[2];
  const float* p3 = (const float*)d_in[3];

  // ws layout: Bn bf16 [8192][128] (2 MB) | pS f32 [4096][8] (128 KB)
  short* Bn = (short*)d_ws;
  float* pS = (float*)((char*)d_ws + (size_t)FOUR_N * DD * sizeof(short));
  float* out = (float*)d_out;

  knorm<<<FOUR_N / 4, 256, 0, stream>>>(p0, p1, p2, p3, Bn, out);
  kgemm<<<dim3(TWO_N / BM, CTG), 1024, 0, stream>>>(Bn, pS);
  kfin<<<TWO_N / BM, 256, 0, stream>>>(Bn, pS, out);
}